// Round 5
// baseline (597.519 us; speedup 1.0000x reference)
//
#include <hip/hip_runtime.h>
#include <hip/hip_bf16.h>
#include <cstddef>
#include <cstdint>

#define B_  32
#define S_  50
#define L_  20
#define R_  16
#define D_  100
#define V_  50000
#define T_  320       // L_*R_
#define RD_ 1600      // R_*D_
#define BS_ 1600      // B_*S_

// ---------------- Phase A: x[bs][j] = sum_l emb0[stories[bs][r*20+l]][d] * in_mult[r*20+l][d]
__global__ __launch_bounds__(512) void x_kernel(
    const int* __restrict__ stories, const float* __restrict__ emb,
    const float* __restrict__ in_mult, float* __restrict__ x)
{
  __shared__ int toks[T_];
  const int bs = blockIdx.x, tid = threadIdx.x;
  const int* st = stories + (size_t)bs * T_;
  if (tid < T_) toks[tid] = st[tid];
  __syncthreads();
  if (tid < 400) {
    const int j4 = tid * 4;
    const int r  = j4 / D_;
    const int d4 = j4 - r * D_;
    float4 acc = make_float4(0.f, 0.f, 0.f, 0.f);
    #pragma unroll
    for (int l = 0; l < 20; ++l) {
      const int t = r * 20 + l;
      const int tok = toks[t];
      if (tok != 0) {
        float4 e = *(const float4*)&emb[(size_t)tok * D_ + d4];
        float4 m = *(const float4*)&in_mult[(size_t)t * D_ + d4];
        acc.x += e.x * m.x; acc.y += e.y * m.y;
        acc.z += e.z * m.z; acc.w += e.w * m.w;
      }
    }
    *(float4*)&x[(size_t)bs * RD_ + j4] = acc;
  }
}

// ---------------- transpose U [1600][100] -> Ut [100][1600]
__global__ void transpose_u_kernel(const float* __restrict__ U, float* __restrict__ Ut) {
  int o = blockIdx.x * 256 + threadIdx.x;
  if (o < RD_ * D_) {
    int k = o / RD_;
    int j = o - k * RD_;
    Ut[o] = U[(size_t)j * D_ + k];
  }
}

// ---------------- v_keys[j] = sum_k keys_flat[k] * Vw[j][k]  (one wave per j)
__global__ __launch_bounds__(256) void vkeys_kernel(
    const float* __restrict__ keys, const float* __restrict__ Vw, float* __restrict__ vk)
{
  int wave = threadIdx.x >> 6, lane = threadIdx.x & 63;
  int j = blockIdx.x * 4 + wave;
  float acc = 0.f;
  for (int k = lane; k < RD_; k += 64)
    acc += keys[k] * Vw[(size_t)j * RD_ + k];
  #pragma unroll
  for (int off = 32; off > 0; off >>= 1) acc += __shfl_down(acc, off);
  if (lane == 0) vk[j] = acc;
}

// ---------------- sign table: table[g][p][j] = sum_{i<4} (+-)Ut[4g+i][j], p bit i => minus
__global__ __launch_bounds__(256) void table_kernel(
    const float* __restrict__ Ut, float* __restrict__ table)
{
  const int g = blockIdx.x >> 4, p = blockIdx.x & 15;
  for (int f = threadIdx.x; f < 400; f += 256) {
    const int j = f * 4;
    float4 t = make_float4(0.f, 0.f, 0.f, 0.f);
    #pragma unroll
    for (int i = 0; i < 4; ++i) {
      float4 uv = *(const float4*)&Ut[(size_t)(4 * g + i) * RD_ + j];
      const float sgn = ((p >> i) & 1) ? -1.f : 1.f;
      t.x += sgn * uv.x; t.y += sgn * uv.y;
      t.z += sgn * uv.z; t.w += sgn * uv.w;
    }
    *(float4*)&table[((size_t)(g * 16 + p)) * RD_ + j] = t;
  }
}

// ---------------- C[m][n] = sum_k A[m][k]*B[n][k]  (NT fp32)
// 64-thread single-wave blocks, 64x64 tile, TM=TN=8 (split 4+32), grid 25x25=625.
// No s_barrier needed; register-staged LDS double buffer hides global latency.
__global__ __launch_bounds__(64) void gemm_nt_kernel(
    const float* __restrict__ A, const float* __restrict__ B, float* __restrict__ C)
{
  __shared__ __align__(16) float As[2][16][68];
  __shared__ __align__(16) float Bs[2][16][68];
  const int tid = threadIdx.x;
  const int bm = blockIdx.y * 64, bn = blockIdx.x * 64;
  const int tx = tid & 7, ty = tid >> 3;
  const int srow = tid >> 2, skq = tid & 3;   // staging coords (i-th group adds 16 rows)

  float4 pa[4], pb[4];
  #pragma unroll
  for (int i = 0; i < 4; ++i) {
    const int r = srow + i * 16;
    pa[i] = *(const float4*)&A[(size_t)(bm + r) * RD_ + skq * 4];
    pb[i] = *(const float4*)&B[(size_t)(bn + r) * RD_ + skq * 4];
  }
  #pragma unroll
  for (int i = 0; i < 4; ++i) {
    const int r = srow + i * 16;
    As[0][skq*4+0][r] = pa[i].x; As[0][skq*4+1][r] = pa[i].y;
    As[0][skq*4+2][r] = pa[i].z; As[0][skq*4+3][r] = pa[i].w;
    Bs[0][skq*4+0][r] = pb[i].x; Bs[0][skq*4+1][r] = pb[i].y;
    Bs[0][skq*4+2][r] = pb[i].z; Bs[0][skq*4+3][r] = pb[i].w;
  }

  float acc[2][2][4][4] = {};
  for (int t = 0; t < 100; ++t) {
    const int cur = t & 1;
    if (t < 99) {
      const int kt = (t + 1) * 16;
      #pragma unroll
      for (int i = 0; i < 4; ++i) {
        const int r = srow + i * 16;
        pa[i] = *(const float4*)&A[(size_t)(bm + r) * RD_ + kt + skq * 4];
        pb[i] = *(const float4*)&B[(size_t)(bn + r) * RD_ + kt + skq * 4];
      }
    }
    #pragma unroll
    for (int k = 0; k < 16; ++k) {
      float4 a0 = *(const float4*)&As[cur][k][ty * 4];
      float4 a1 = *(const float4*)&As[cur][k][ty * 4 + 32];
      float4 b0 = *(const float4*)&Bs[cur][k][tx * 4];
      float4 b1 = *(const float4*)&Bs[cur][k][tx * 4 + 32];
      float am[8] = {a0.x,a0.y,a0.z,a0.w,a1.x,a1.y,a1.z,a1.w};
      float bv[8] = {b0.x,b0.y,b0.z,b0.w,b1.x,b1.y,b1.z,b1.w};
      #pragma unroll
      for (int qm = 0; qm < 2; ++qm)
        #pragma unroll
        for (int i = 0; i < 4; ++i)
          #pragma unroll
          for (int qn = 0; qn < 2; ++qn)
            #pragma unroll
            for (int j = 0; j < 4; ++j)
              acc[qm][qn][i][j] += am[qm*4+i] * bv[qn*4+j];
    }
    if (t < 99) {
      const int nxt = cur ^ 1;
      #pragma unroll
      for (int i = 0; i < 4; ++i) {
        const int r = srow + i * 16;
        As[nxt][skq*4+0][r] = pa[i].x; As[nxt][skq*4+1][r] = pa[i].y;
        As[nxt][skq*4+2][r] = pa[i].z; As[nxt][skq*4+3][r] = pa[i].w;
        Bs[nxt][skq*4+0][r] = pb[i].x; Bs[nxt][skq*4+1][r] = pb[i].y;
        Bs[nxt][skq*4+2][r] = pb[i].z; Bs[nxt][skq*4+3][r] = pb[i].w;
      }
    }
  }
  #pragma unroll
  for (int qm = 0; qm < 2; ++qm)
    #pragma unroll
    for (int i = 0; i < 4; ++i) {
      const int gr = bm + qm * 32 + ty * 4 + i;
      #pragma unroll
      for (int qn = 0; qn < 2; ++qn)
        *(float4*)&C[(size_t)gr * RD_ + bn + qn * 32 + tx * 4] =
            make_float4(acc[qm][qn][i][0], acc[qm][qn][i][1],
                        acc[qm][qn][i][2], acc[qm][qn][i][3]);
    }
}

// ---------------- scan: one block per b. Step 0 direct u-dot, steps>=1 via sign table.
// Next-step x/Wall rows software-prefetched into registers.
__global__ __launch_bounds__(512) void scan_kernel(
    const float* __restrict__ x,       // [BS_][RD_]
    const float* __restrict__ Wall,    // [BS_][RD_]
    const float* __restrict__ Ut,      // [D_][RD_]
    const float* __restrict__ table,   // [25*16][RD_]
    const float* __restrict__ vkeys,   // [RD_]
    const float* __restrict__ keys,    // [RD_]
    const float* __restrict__ init_state, // [D_]
    const float* __restrict__ alpha_in_p,
    float* __restrict__ state_out)     // [B_][D_]
{
  const int b = blockIdx.x, tid = threadIdx.x;
  __shared__ __align__(16) float s_state[D_];
  __shared__ __align__(16) float s_c[RD_];
  __shared__ int s_idx[25];
  const float alpha = alpha_in_p[0];
  const bool active = (tid < 400);
  const int j4 = tid * 4;
  const int d4 = (j4 % D_);
  float4 kk = make_float4(0.f,0.f,0.f,0.f), vv = kk;
  float4 sent_c = kk, w_c = kk;
  if (active) {
    kk = *(const float4*)&keys[j4];
    vv = *(const float4*)&vkeys[j4];
    sent_c = *(const float4*)&x[(size_t)b * S_ * RD_ + j4];
    w_c    = *(const float4*)&Wall[(size_t)b * S_ * RD_ + j4];
  }
  if (tid < D_) s_state[tid] = init_state[tid];
  __syncthreads();

  for (int s = 0; s < S_; ++s) {
    float4 sent_n = make_float4(0.f,0.f,0.f,0.f), w_n = sent_n;
    if (active && s + 1 < S_) {
      const size_t nrow = ((size_t)b * S_ + s + 1) * RD_;
      sent_n = *(const float4*)&x[nrow + j4];     // prefetch next step
      w_n    = *(const float4*)&Wall[nrow + j4];
    }
    if (active) {
      float4 u = make_float4(0.f,0.f,0.f,0.f);
      if (s == 0) {
        #pragma unroll
        for (int q = 0; q < 25; ++q) {
          float4 stv = *(const float4*)&s_state[4 * q];   // broadcast b128
          float4 u0 = *(const float4*)&Ut[(size_t)(4*q+0) * RD_ + j4];
          float4 u1 = *(const float4*)&Ut[(size_t)(4*q+1) * RD_ + j4];
          float4 u2 = *(const float4*)&Ut[(size_t)(4*q+2) * RD_ + j4];
          float4 u3 = *(const float4*)&Ut[(size_t)(4*q+3) * RD_ + j4];
          u.x += stv.x*u0.x + stv.y*u1.x + stv.z*u2.x + stv.w*u3.x;
          u.y += stv.x*u0.y + stv.y*u1.y + stv.z*u2.y + stv.w*u3.y;
          u.z += stv.x*u0.z + stv.y*u1.z + stv.z*u2.z + stv.w*u3.z;
          u.w += stv.x*u0.w + stv.y*u1.w + stv.z*u2.w + stv.w*u3.w;
        }
      } else {
        #pragma unroll
        for (int g = 0; g < 25; ++g) {
          float4 tv = *(const float4*)&table[(size_t)((g << 4) + s_idx[g]) * RD_ + j4];
          u.x += tv.x; u.y += tv.y; u.z += tv.z; u.w += tv.w;
        }
      }
      float4 sd = *(const float4*)&s_state[d4];
      float zx = sent_c.x * sd.x + sent_c.x * kk.x;
      float zy = sent_c.y * sd.y + sent_c.y * kk.y;
      float zz = sent_c.z * sd.z + sent_c.z * kk.z;
      float zw = sent_c.w * sd.w + sent_c.w * kk.w;
      float gx = 1.0f / (1.0f + expf(-zx));
      float gy = 1.0f / (1.0f + expf(-zy));
      float gz = 1.0f / (1.0f + expf(-zz));
      float gw = 1.0f / (1.0f + expf(-zw));
      float cx = u.x + vv.x + w_c.x; cx = cx >= 0.f ? cx : alpha * cx;
      float cy = u.y + vv.y + w_c.y; cy = cy >= 0.f ? cy : alpha * cy;
      float cz = u.z + vv.z + w_c.z; cz = cz >= 0.f ? cz : alpha * cz;
      float cw = u.w + vv.w + w_c.w; cw = cw >= 0.f ? cw : alpha * cw;
      float4 cc;
      cc.x = (gx == 0.5f) ? 0.f : cx * gx;
      cc.y = (gy == 0.5f) ? 0.f : cy * gy;
      cc.z = (gz == 0.5f) ? 0.f : cz * gz;
      cc.w = (gw == 0.5f) ? 0.f : cw * gw;
      *(float4*)&s_c[j4] = cc;
    }
    __syncthreads();
    if (tid < D_) {
      float csum = 0.f;
      #pragma unroll
      for (int r = 0; r < R_; ++r) csum += s_c[r * D_ + tid];
      float v = s_state[tid] + csum;
      v = v / sqrtf(v * v);   // faithful: torch.norm over singleton dim -> sign
      s_state[tid] = v;
    }
    __syncthreads();
    if (tid < 25) {
      float4 sv = *(const float4*)&s_state[4 * tid];
      s_idx[tid] = (sv.x < 0.f ? 1 : 0) | (sv.y < 0.f ? 2 : 0)
                 | (sv.z < 0.f ? 4 : 0) | (sv.w < 0.f ? 8 : 0);
    }
    __syncthreads();
    sent_c = sent_n; w_c = w_n;
  }
  if (tid < D_) state_out[(size_t)b * D_ + tid] = s_state[tid];
}

// ---------------- h[b][d] = prelu( q[b][d] + sum_k state[b][k]*Hw[d][k], alpha_q )
__global__ void head_kernel(
    const int* __restrict__ queries, const float* __restrict__ emb,
    const float* __restrict__ q_mult, const float* __restrict__ state_g,
    const float* __restrict__ Hw, const float* __restrict__ alpha_q_p,
    float* __restrict__ h_g)
{
  int b = blockIdx.x, d = threadIdx.x;
  if (d >= D_) return;
  float q = 0.f;
  #pragma unroll
  for (int l = 0; l < L_; ++l) {
    int tok = queries[b * L_ + l];
    if (tok != 0) q += emb[(size_t)tok * D_ + d] * q_mult[l * D_ + d];
  }
  float acc = 0.f;
  const float* st = state_g + (size_t)b * D_;
  #pragma unroll 4
  for (int k = 0; k < D_; ++k) acc += st[k] * Hw[(size_t)d * D_ + k];
  float h = q + acc;
  float alpha = alpha_q_p[0];
  h = h >= 0.f ? h : alpha * h;
  h_g[(size_t)b * D_ + d] = h;
}

// ---------------- out[b][v] = sum_k h[b][k] * Rw[v][k]   (v-tile=32 staged in LDS)
__global__ __launch_bounds__(256) void out_kernel(
    const float* __restrict__ h_g, const float* __restrict__ Rw, float* __restrict__ out)
{
  __shared__ __align__(16) float sh[B_ * D_];    // 3200
  __shared__ __align__(16) float sr[32 * D_];    // 3200
  int tid = threadIdx.x;
  int v0 = blockIdx.x * 32;
  for (int i = tid; i < B_ * D_; i += 256) sh[i] = h_g[i];
  int nrows = V_ - v0; if (nrows > 32) nrows = 32;
  for (int i = tid; i < nrows * D_; i += 256) sr[i] = Rw[(size_t)v0 * D_ + i];
  __syncthreads();
  const float4* sh4 = (const float4*)sh;
  const float4* sr4 = (const float4*)sr;
  int tv = (tid & 15) * 2;
  int tb = (tid >> 4) * 2;
  float a00 = 0.f, a01 = 0.f, a10 = 0.f, a11 = 0.f;
  #pragma unroll
  for (int kc = 0; kc < 25; ++kc) {
    float4 h0 = sh4[tb * 25 + kc];
    float4 h1 = sh4[(tb + 1) * 25 + kc];
    float4 r0 = sr4[tv * 25 + kc];
    float4 r1 = sr4[(tv + 1) * 25 + kc];
    a00 += h0.x*r0.x + h0.y*r0.y + h0.z*r0.z + h0.w*r0.w;
    a01 += h0.x*r1.x + h0.y*r1.y + h0.z*r1.z + h0.w*r1.w;
    a10 += h1.x*r0.x + h1.y*r0.y + h1.z*r0.z + h1.w*r0.w;
    a11 += h1.x*r1.x + h1.y*r1.y + h1.z*r1.z + h1.w*r1.w;
  }
  if (tv < nrows) {
    out[(size_t)tb * V_ + v0 + tv] = a00;
    out[(size_t)(tb + 1) * V_ + v0 + tv] = a10;
  }
  if (tv + 1 < nrows) {
    out[(size_t)tb * V_ + v0 + tv + 1] = a01;
    out[(size_t)(tb + 1) * V_ + v0 + tv + 1] = a11;
  }
}

extern "C" void kernel_launch(void* const* d_in, const int* in_sizes, int n_in,
                              void* d_out, int out_size, void* d_ws, size_t ws_size,
                              hipStream_t stream) {
  const int*   stories    = (const int*)  d_in[0];
  const int*   queries    = (const int*)  d_in[1];
  const float* emb        = (const float*)d_in[2];
  const float* in_mult    = (const float*)d_in[3];
  const float* q_mult     = (const float*)d_in[4];
  const float* keys       = (const float*)d_in[5];
  const float* init_state = (const float*)d_in[6];
  const float* U          = (const float*)d_in[7];
  const float* Vw         = (const float*)d_in[8];
  const float* Ww         = (const float*)d_in[9];
  const float* Hw         = (const float*)d_in[10];
  const float* Rw         = (const float*)d_in[11];
  const float* alpha_in   = (const float*)d_in[12];
  const float* alpha_q    = (const float*)d_in[13];
  float* out = (float*)d_out;

  char* ws = (char*)d_ws;
  float* x     = (float*)(ws);               // 10,240,000 B
  float* Wall  = (float*)(ws + 10240000);    // 10,240,000 B
  float* Ut    = (float*)(ws + 20480000);    //    640,000 B
  float* table = (float*)(ws + 21120000);    //  2,560,000 B
  float* vk    = (float*)(ws + 23680000);    //      6,400 B
  float* state = (float*)(ws + 23686400);    //     12,800 B
  float* hbuf  = (float*)(ws + 23699200);    //     12,800 B
  // total 23,712,000 B

  x_kernel<<<BS_, 512, 0, stream>>>(stories, emb, in_mult, x);
  transpose_u_kernel<<<(RD_ * D_ + 255) / 256, 256, 0, stream>>>(U, Ut);
  vkeys_kernel<<<RD_ / 4, 256, 0, stream>>>(keys, Vw, vk);
  gemm_nt_kernel<<<dim3(25, 25), 64, 0, stream>>>(x, Ww, Wall);
  table_kernel<<<400, 256, 0, stream>>>(Ut, table);
  scan_kernel<<<B_, 512, 0, stream>>>(x, Wall, Ut, table, vk, keys, init_state,
                                      alpha_in, state);
  head_kernel<<<B_, 128, 0, stream>>>(queries, emb, q_mult, state, Hw, alpha_q, hbuf);
  out_kernel<<<(V_ + 31) / 32, 256, 0, stream>>>(hbuf, Rw, out);
}

// Round 6
// 534.121 us; speedup vs baseline: 1.1187x; 1.1187x over previous
//
#include <hip/hip_runtime.h>
#include <hip/hip_bf16.h>
#include <cstddef>
#include <cstdint>

#define B_  32
#define S_  50
#define L_  20
#define R_  16
#define D_  100
#define V_  50000
#define T_  320       // L_*R_
#define RD_ 1600      // R_*D_
#define BS_ 1600      // B_*S_

// ---------------- Phase A: x[bs][j] = sum_l emb0[stories[bs][r*20+l]][d] * in_mult[r*20+l][d]
__global__ __launch_bounds__(512) void x_kernel(
    const int* __restrict__ stories, const float* __restrict__ emb,
    const float* __restrict__ in_mult, float* __restrict__ x)
{
  __shared__ int toks[T_];
  const int bs = blockIdx.x, tid = threadIdx.x;
  const int* st = stories + (size_t)bs * T_;
  if (tid < T_) toks[tid] = st[tid];
  __syncthreads();
  if (tid < 400) {
    const int j4 = tid * 4;
    const int r  = j4 / D_;
    const int d4 = j4 - r * D_;
    float4 acc = make_float4(0.f, 0.f, 0.f, 0.f);
    #pragma unroll
    for (int l = 0; l < 20; ++l) {
      const int t = r * 20 + l;
      const int tok = toks[t];
      if (tok != 0) {
        float4 e = *(const float4*)&emb[(size_t)tok * D_ + d4];
        float4 m = *(const float4*)&in_mult[(size_t)t * D_ + d4];
        acc.x += e.x * m.x; acc.y += e.y * m.y;
        acc.z += e.z * m.z; acc.w += e.w * m.w;
      }
    }
    *(float4*)&x[(size_t)bs * RD_ + j4] = acc;
  }
}

// ---------------- transpose U [1600][100] -> Ut [100][1600]
__global__ void transpose_u_kernel(const float* __restrict__ U, float* __restrict__ Ut) {
  int o = blockIdx.x * 256 + threadIdx.x;
  if (o < RD_ * D_) {
    int k = o / RD_;
    int j = o - k * RD_;
    Ut[o] = U[(size_t)j * D_ + k];
  }
}

// ---------------- v_keys[j] = sum_k keys_flat[k] * Vw[j][k]  (one wave per j)
__global__ __launch_bounds__(256) void vkeys_kernel(
    const float* __restrict__ keys, const float* __restrict__ Vw, float* __restrict__ vk)
{
  int wave = threadIdx.x >> 6, lane = threadIdx.x & 63;
  int j = blockIdx.x * 4 + wave;
  float acc = 0.f;
  for (int k = lane; k < RD_; k += 64)
    acc += keys[k] * Vw[(size_t)j * RD_ + k];
  #pragma unroll
  for (int off = 32; off > 0; off >>= 1) acc += __shfl_down(acc, off);
  if (lane == 0) vk[j] = acc;
}

// ---------------- sign table: table[g][p][j] = sum_{i<4} (+-)Ut[4g+i][j], p bit i => minus
__global__ __launch_bounds__(256) void table_kernel(
    const float* __restrict__ Ut, float* __restrict__ table)
{
  const int g = blockIdx.x >> 4, p = blockIdx.x & 15;
  for (int f = threadIdx.x; f < 400; f += 256) {
    const int j = f * 4;
    float4 t = make_float4(0.f, 0.f, 0.f, 0.f);
    #pragma unroll
    for (int i = 0; i < 4; ++i) {
      float4 uv = *(const float4*)&Ut[(size_t)(4 * g + i) * RD_ + j];
      const float sgn = ((p >> i) & 1) ? -1.f : 1.f;
      t.x += sgn * uv.x; t.y += sgn * uv.y;
      t.z += sgn * uv.z; t.w += sgn * uv.w;
    }
    *(float4*)&table[((size_t)(g * 16 + p)) * RD_ + j] = t;
  }
}

// ---------------- C[m][n] = sum_k A[m][k]*B[n][k]  (NT fp32, 64x64 tile, 256 thr,
// TM=TN=4, BK=32, LDS double-buffered: one barrier/stage, VALU-bound inner loop)
__global__ __launch_bounds__(256) void gemm_nt_kernel(
    const float* __restrict__ A, const float* __restrict__ B, float* __restrict__ C)
{
  __shared__ __align__(16) float As[2][32][68];
  __shared__ __align__(16) float Bs[2][32][68];
  const int tid = threadIdx.x;
  const int bm = blockIdx.y * 64, bn = blockIdx.x * 64;
  const int tx = tid & 15, ty = tid >> 4;
  const int r = tid >> 2, c = tid & 3;   // staging: row r, float-offset c*8

  const float* Ar = &A[(size_t)(bm + r) * RD_ + c * 8];
  const float* Br = &B[(size_t)(bn + r) * RD_ + c * 8];

  float4 a0 = *(const float4*)Ar,      a1 = *(const float4*)(Ar + 4);
  float4 b0 = *(const float4*)Br,      b1 = *(const float4*)(Br + 4);
  {
    #pragma unroll
    for (int i = 0; i < 4; ++i) {
      As[0][c*8 + i][r]     = (&a0.x)[i];
      As[0][c*8 + 4 + i][r] = (&a1.x)[i];
      Bs[0][c*8 + i][r]     = (&b0.x)[i];
      Bs[0][c*8 + 4 + i][r] = (&b1.x)[i];
    }
  }
  __syncthreads();

  float acc[4][4] = {};
  for (int t = 0; t < 50; ++t) {
    const int cur = t & 1;
    if (t < 49) {                       // prefetch next stage into registers
      const float* An = Ar + (t + 1) * 32;
      const float* Bn = Br + (t + 1) * 32;
      a0 = *(const float4*)An; a1 = *(const float4*)(An + 4);
      b0 = *(const float4*)Bn; b1 = *(const float4*)(Bn + 4);
    }
    #pragma unroll
    for (int k = 0; k < 32; ++k) {
      float4 av = *(const float4*)&As[cur][k][ty * 4];
      float4 bv = *(const float4*)&Bs[cur][k][tx * 4];
      acc[0][0] += av.x*bv.x; acc[0][1] += av.x*bv.y; acc[0][2] += av.x*bv.z; acc[0][3] += av.x*bv.w;
      acc[1][0] += av.y*bv.x; acc[1][1] += av.y*bv.y; acc[1][2] += av.y*bv.z; acc[1][3] += av.y*bv.w;
      acc[2][0] += av.z*bv.x; acc[2][1] += av.z*bv.y; acc[2][2] += av.z*bv.z; acc[2][3] += av.z*bv.w;
      acc[3][0] += av.w*bv.x; acc[3][1] += av.w*bv.y; acc[3][2] += av.w*bv.z; acc[3][3] += av.w*bv.w;
    }
    if (t < 49) {
      const int nxt = cur ^ 1;
      #pragma unroll
      for (int i = 0; i < 4; ++i) {
        As[nxt][c*8 + i][r]     = (&a0.x)[i];
        As[nxt][c*8 + 4 + i][r] = (&a1.x)[i];
        Bs[nxt][c*8 + i][r]     = (&b0.x)[i];
        Bs[nxt][c*8 + 4 + i][r] = (&b1.x)[i];
      }
    }
    __syncthreads();
  }
  #pragma unroll
  for (int i = 0; i < 4; ++i) {
    *(float4*)&C[(size_t)(bm + ty*4 + i) * RD_ + bn + tx*4] =
        make_float4(acc[i][0], acc[i][1], acc[i][2], acc[i][3]);
  }
}

// ---------------- scan: one block per b. Step 0 direct u-dot, steps>=1 via sign table.
// Next-step x/Wall rows software-prefetched into registers.
__global__ __launch_bounds__(512) void scan_kernel(
    const float* __restrict__ x,       // [BS_][RD_]
    const float* __restrict__ Wall,    // [BS_][RD_]
    const float* __restrict__ Ut,      // [D_][RD_]
    const float* __restrict__ table,   // [25*16][RD_]
    const float* __restrict__ vkeys,   // [RD_]
    const float* __restrict__ keys,    // [RD_]
    const float* __restrict__ init_state, // [D_]
    const float* __restrict__ alpha_in_p,
    float* __restrict__ state_out)     // [B_][D_]
{
  const int b = blockIdx.x, tid = threadIdx.x;
  __shared__ __align__(16) float s_state[D_];
  __shared__ __align__(16) float s_c[RD_];
  __shared__ int s_idx[25];
  const float alpha = alpha_in_p[0];
  const bool active = (tid < 400);
  const int j4 = tid * 4;
  const int d4 = (j4 % D_);
  float4 kk = make_float4(0.f,0.f,0.f,0.f), vv = kk;
  float4 sent_c = kk, w_c = kk;
  if (active) {
    kk = *(const float4*)&keys[j4];
    vv = *(const float4*)&vkeys[j4];
    sent_c = *(const float4*)&x[(size_t)b * S_ * RD_ + j4];
    w_c    = *(const float4*)&Wall[(size_t)b * S_ * RD_ + j4];
  }
  if (tid < D_) s_state[tid] = init_state[tid];
  __syncthreads();

  for (int s = 0; s < S_; ++s) {
    float4 sent_n = make_float4(0.f,0.f,0.f,0.f), w_n = sent_n;
    if (active && s + 1 < S_) {
      const size_t nrow = ((size_t)b * S_ + s + 1) * RD_;
      sent_n = *(const float4*)&x[nrow + j4];     // prefetch next step
      w_n    = *(const float4*)&Wall[nrow + j4];
    }
    if (active) {
      float4 u = make_float4(0.f,0.f,0.f,0.f);
      if (s == 0) {
        #pragma unroll
        for (int q = 0; q < 25; ++q) {
          float4 stv = *(const float4*)&s_state[4 * q];   // broadcast b128
          float4 u0 = *(const float4*)&Ut[(size_t)(4*q+0) * RD_ + j4];
          float4 u1 = *(const float4*)&Ut[(size_t)(4*q+1) * RD_ + j4];
          float4 u2 = *(const float4*)&Ut[(size_t)(4*q+2) * RD_ + j4];
          float4 u3 = *(const float4*)&Ut[(size_t)(4*q+3) * RD_ + j4];
          u.x += stv.x*u0.x + stv.y*u1.x + stv.z*u2.x + stv.w*u3.x;
          u.y += stv.x*u0.y + stv.y*u1.y + stv.z*u2.y + stv.w*u3.y;
          u.z += stv.x*u0.z + stv.y*u1.z + stv.z*u2.z + stv.w*u3.z;
          u.w += stv.x*u0.w + stv.y*u1.w + stv.z*u2.w + stv.w*u3.w;
        }
      } else {
        #pragma unroll
        for (int g = 0; g < 25; ++g) {
          float4 tv = *(const float4*)&table[(size_t)((g << 4) + s_idx[g]) * RD_ + j4];
          u.x += tv.x; u.y += tv.y; u.z += tv.z; u.w += tv.w;
        }
      }
      float4 sd = *(const float4*)&s_state[d4];
      float zx = sent_c.x * sd.x + sent_c.x * kk.x;
      float zy = sent_c.y * sd.y + sent_c.y * kk.y;
      float zz = sent_c.z * sd.z + sent_c.z * kk.z;
      float zw = sent_c.w * sd.w + sent_c.w * kk.w;
      float gx = 1.0f / (1.0f + expf(-zx));
      float gy = 1.0f / (1.0f + expf(-zy));
      float gz = 1.0f / (1.0f + expf(-zz));
      float gw = 1.0f / (1.0f + expf(-zw));
      float cx = u.x + vv.x + w_c.x; cx = cx >= 0.f ? cx : alpha * cx;
      float cy = u.y + vv.y + w_c.y; cy = cy >= 0.f ? cy : alpha * cy;
      float cz = u.z + vv.z + w_c.z; cz = cz >= 0.f ? cz : alpha * cz;
      float cw = u.w + vv.w + w_c.w; cw = cw >= 0.f ? cw : alpha * cw;
      float4 cc;
      cc.x = (gx == 0.5f) ? 0.f : cx * gx;
      cc.y = (gy == 0.5f) ? 0.f : cy * gy;
      cc.z = (gz == 0.5f) ? 0.f : cz * gz;
      cc.w = (gw == 0.5f) ? 0.f : cw * gw;
      *(float4*)&s_c[j4] = cc;
    }
    __syncthreads();
    if (tid < D_) {
      float csum = 0.f;
      #pragma unroll
      for (int r = 0; r < R_; ++r) csum += s_c[r * D_ + tid];
      float v = s_state[tid] + csum;
      v = v / sqrtf(v * v);   // faithful: torch.norm over singleton dim -> sign
      s_state[tid] = v;
    }
    __syncthreads();
    if (tid < 25) {
      float4 sv = *(const float4*)&s_state[4 * tid];
      s_idx[tid] = (sv.x < 0.f ? 1 : 0) | (sv.y < 0.f ? 2 : 0)
                 | (sv.z < 0.f ? 4 : 0) | (sv.w < 0.f ? 8 : 0);
    }
    __syncthreads();
    sent_c = sent_n; w_c = w_n;
  }
  if (tid < D_) state_out[(size_t)b * D_ + tid] = s_state[tid];
}

// ---------------- h[b][d] = prelu( q[b][d] + sum_k state[b][k]*Hw[d][k], alpha_q )
__global__ void head_kernel(
    const int* __restrict__ queries, const float* __restrict__ emb,
    const float* __restrict__ q_mult, const float* __restrict__ state_g,
    const float* __restrict__ Hw, const float* __restrict__ alpha_q_p,
    float* __restrict__ h_g)
{
  int b = blockIdx.x, d = threadIdx.x;
  if (d >= D_) return;
  float q = 0.f;
  #pragma unroll
  for (int l = 0; l < L_; ++l) {
    int tok = queries[b * L_ + l];
    if (tok != 0) q += emb[(size_t)tok * D_ + d] * q_mult[l * D_ + d];
  }
  float acc = 0.f;
  const float* st = state_g + (size_t)b * D_;
  #pragma unroll 4
  for (int k = 0; k < D_; ++k) acc += st[k] * Hw[(size_t)d * D_ + k];
  float h = q + acc;
  float alpha = alpha_q_p[0];
  h = h >= 0.f ? h : alpha * h;
  h_g[(size_t)b * D_ + d] = h;
}

// ---------------- out[b][v] = sum_k h[b][k] * Rw[v][k]   (v-tile=32 staged in LDS)
__global__ __launch_bounds__(256) void out_kernel(
    const float* __restrict__ h_g, const float* __restrict__ Rw, float* __restrict__ out)
{
  __shared__ __align__(16) float sh[B_ * D_];    // 3200
  __shared__ __align__(16) float sr[32 * D_];    // 3200
  int tid = threadIdx.x;
  int v0 = blockIdx.x * 32;
  for (int i = tid; i < B_ * D_; i += 256) sh[i] = h_g[i];
  int nrows = V_ - v0; if (nrows > 32) nrows = 32;
  for (int i = tid; i < nrows * D_; i += 256) sr[i] = Rw[(size_t)v0 * D_ + i];
  __syncthreads();
  const float4* sh4 = (const float4*)sh;
  const float4* sr4 = (const float4*)sr;
  int tv = (tid & 15) * 2;
  int tb = (tid >> 4) * 2;
  float a00 = 0.f, a01 = 0.f, a10 = 0.f, a11 = 0.f;
  #pragma unroll
  for (int kc = 0; kc < 25; ++kc) {
    float4 h0 = sh4[tb * 25 + kc];
    float4 h1 = sh4[(tb + 1) * 25 + kc];
    float4 r0 = sr4[tv * 25 + kc];
    float4 r1 = sr4[(tv + 1) * 25 + kc];
    a00 += h0.x*r0.x + h0.y*r0.y + h0.z*r0.z + h0.w*r0.w;
    a01 += h0.x*r1.x + h0.y*r1.y + h0.z*r1.z + h0.w*r1.w;
    a10 += h1.x*r0.x + h1.y*r0.y + h1.z*r0.z + h1.w*r0.w;
    a11 += h1.x*r1.x + h1.y*r1.y + h1.z*r1.z + h1.w*r1.w;
  }
  if (tv < nrows) {
    out[(size_t)tb * V_ + v0 + tv] = a00;
    out[(size_t)(tb + 1) * V_ + v0 + tv] = a10;
  }
  if (tv + 1 < nrows) {
    out[(size_t)tb * V_ + v0 + tv + 1] = a01;
    out[(size_t)(tb + 1) * V_ + v0 + tv + 1] = a11;
  }
}

extern "C" void kernel_launch(void* const* d_in, const int* in_sizes, int n_in,
                              void* d_out, int out_size, void* d_ws, size_t ws_size,
                              hipStream_t stream) {
  const int*   stories    = (const int*)  d_in[0];
  const int*   queries    = (const int*)  d_in[1];
  const float* emb        = (const float*)d_in[2];
  const float* in_mult    = (const float*)d_in[3];
  const float* q_mult     = (const float*)d_in[4];
  const float* keys       = (const float*)d_in[5];
  const float* init_state = (const float*)d_in[6];
  const float* U          = (const float*)d_in[7];
  const float* Vw         = (const float*)d_in[8];
  const float* Ww         = (const float*)d_in[9];
  const float* Hw         = (const float*)d_in[10];
  const float* Rw         = (const float*)d_in[11];
  const float* alpha_in   = (const float*)d_in[12];
  const float* alpha_q    = (const float*)d_in[13];
  float* out = (float*)d_out;

  char* ws = (char*)d_ws;
  float* x     = (float*)(ws);               // 10,240,000 B
  float* Wall  = (float*)(ws + 10240000);    // 10,240,000 B
  float* Ut    = (float*)(ws + 20480000);    //    640,000 B
  float* table = (float*)(ws + 21120000);    //  2,560,000 B
  float* vk    = (float*)(ws + 23680000);    //      6,400 B
  float* state = (float*)(ws + 23686400);    //     12,800 B
  float* hbuf  = (float*)(ws + 23699200);    //     12,800 B
  // total 23,712,000 B

  x_kernel<<<BS_, 512, 0, stream>>>(stories, emb, in_mult, x);
  transpose_u_kernel<<<(RD_ * D_ + 255) / 256, 256, 0, stream>>>(U, Ut);
  vkeys_kernel<<<RD_ / 4, 256, 0, stream>>>(keys, Vw, vk);
  gemm_nt_kernel<<<dim3(25, 25), 256, 0, stream>>>(x, Ww, Wall);
  table_kernel<<<400, 256, 0, stream>>>(Ut, table);
  scan_kernel<<<B_, 512, 0, stream>>>(x, Wall, Ut, table, vk, keys, init_state,
                                      alpha_in, state);
  head_kernel<<<B_, 128, 0, stream>>>(queries, emb, q_mult, state, Hw, alpha_q, hbuf);
  out_kernel<<<(V_ + 31) / 32, 256, 0, stream>>>(hbuf, Rw, out);
}